// Round 13
// baseline (185.280 us; speedup 1.0000x reference)
//
#include <hip/hip_runtime.h>
#include <math.h>

#define BB   64
#define SS   576
#define DD   768
#define KTOP 63
#define KEEP 64
#define HH   128
#define NROW (BB*KEEP + BB)   // 4160 = 65*64
#define SCH  24               // pooled-sum chunk count (grid.y)

typedef unsigned long long ull;

// ---------------- K1: cls attention scores (f64 accumulate for exact ranking) ---
__global__ __launch_bounds__(256) void k_scores(const float* __restrict__ cls,
                                                const float* __restrict__ fm,
                                                float* __restrict__ scores)
{
  int gw = (blockIdx.x * blockDim.x + threadIdx.x) >> 6;   // one wave per (b,s)
  int lane = threadIdx.x & 63;
  if (gw >= BB * SS) return;
  int b = gw / SS, s = gw - b * SS;
  const float4* frow = (const float4*)(fm + ((size_t)b * SS + s) * DD);
  const float4* crow = (const float4*)(cls + (size_t)b * DD);
  double acc = 0.0;
#pragma unroll
  for (int j = 0; j < 3; ++j) {
    float4 f = frow[lane + 64 * j];
    float4 c = crow[lane + 64 * j];
    acc += (double)f.x * c.x + (double)f.y * c.y + (double)f.z * c.z + (double)f.w * c.w;
  }
#pragma unroll
  for (int off = 32; off > 0; off >>= 1) acc += __shfl_down(acc, off, 64);
  if (lane == 0) scores[(size_t)b * SS + s] = (float)acc;
}

// ---------------- K2: rank top-63 + softmax weights + survivor compaction ------
// One 576-thread block per batch. rank = #{keys > key_s} (unique keys -> exact
// jax.lax.top_k order). w' = e/Z (0 for selected, matching f32 exp(-1e4)
// underflow). Rows with w' > 1e-10 are compacted (stable, ascending s) into
// (cidx, cw); skipped mass <= ~5e-9. Also zeroes the ae1 completion counters
// (stream-ordered before k_ae1).
__global__ __launch_bounds__(576) void k_rank(const float* __restrict__ scores,
                                              int* __restrict__ idxout,
                                              int* __restrict__ cidx,
                                              float* __restrict__ cw,
                                              int* __restrict__ ccount,
                                              int* __restrict__ cnt)
{
  __shared__ ull keys[SS];
  __shared__ float redm[9], redz[9];
  __shared__ unsigned wcnt[9];
  int b = blockIdx.x, tid = threadIdx.x;          // tid == s (0..575)
  int lane = tid & 63, wid = tid >> 6;            // 9 waves
  if (tid == 0) cnt[b] = 0;                       // zero completion counters
  if (b == 0 && tid == 1) cnt[64] = 0;
  float sc = scores[(size_t)b * SS + tid];
  unsigned int u = __float_as_uint(sc);
  u = (u & 0x80000000u) ? ~u : (u | 0x80000000u); // order-preserving map
  ull key = ((ull)u << 32) | (ull)(0xFFFFFFFFu - (unsigned)tid);
  keys[tid] = key;
  __syncthreads();
  int rank = 0;
#pragma unroll 8
  for (int s = 0; s < SS; ++s) rank += (keys[s] > key) ? 1 : 0;   // LDS broadcast
  bool sel = rank < KTOP;
  if (sel) idxout[b * KEEP + rank] = tid;
  // max over unselected (selected logits are sc-10000 -> never the max)
  float m = sel ? -1e30f : sc;
#pragma unroll
  for (int off = 32; off; off >>= 1) m = fmaxf(m, __shfl_xor(m, off, 64));
  if (lane == 0) redm[wid] = m;
  __syncthreads();
  float M = redm[0];
#pragma unroll
  for (int i = 1; i < 9; ++i) M = fmaxf(M, redm[i]);
  float e = sel ? 0.f : expf(sc - M);
  float z = e;
#pragma unroll
  for (int off = 32; off; off >>= 1) z += __shfl_xor(z, off, 64);
  if (lane == 0) redz[wid] = z;
  __syncthreads();
  float Z = redz[0];
#pragma unroll
  for (int i = 1; i < 9; ++i) Z += redz[i];
  float w = e / Z;
  // ---- compaction of survivors ----
  bool keep = w > 1e-10f;
  ull ball = __ballot(keep);
  int wpre = __popcll(ball & ((1ull << lane) - 1ull));
  if (lane == 0) wcnt[wid] = (unsigned)__popcll(ball);
  __syncthreads();
  int base = 0;
#pragma unroll
  for (int i = 0; i < 9; ++i) base += (i < wid) ? (int)wcnt[i] : 0;
  if (keep) {
    int pos = base + wpre;
    cidx[(size_t)b * SS + pos] = tid;
    cw[(size_t)b * SS + pos] = w;
  }
  if (tid == 0) {
    int tot = 0;
#pragma unroll
    for (int i = 0; i < 9; ++i) tot += (int)wcnt[i];
    ccount[b] = tot;
  }
}

// ---------------- K3: sparse pooled-token partial sums -------------------------
// grid (64, 24) x 192 thr. Chunk p sums survivor rows r = p, p+24, ... Each row
// read is a coalesced 3 KB segment (192 x float4).
__global__ __launch_bounds__(192) void k_extra2(const int* __restrict__ cidx,
                                                const float* __restrict__ cw,
                                                const int* __restrict__ ccount,
                                                const float* __restrict__ fm,
                                                float* __restrict__ epart)
{
  int b = blockIdx.x, p = blockIdx.y, tid = threadIdx.x;   // tid = float4 col
  int n = ccount[b];
  const float* fb = fm + (size_t)b * SS * DD + tid * 4;
  float4 acc = make_float4(0.f, 0.f, 0.f, 0.f);
  for (int r = p; r < n; r += SCH) {
    float w = cw[(size_t)b * SS + r];                      // uniform broadcast
    int s = cidx[(size_t)b * SS + r];
    float4 v = *(const float4*)(fb + (size_t)s * DD);
    acc.x = fmaf(w, v.x, acc.x); acc.y = fmaf(w, v.y, acc.y);
    acc.z = fmaf(w, v.z, acc.z); acc.w = fmaf(w, v.w, acc.w);
  }
  *(float4*)(epart + (size_t)(b * SCH + p) * DD + tid * 4) = acc;
}

// ---------------- K4: partial[y] = X @ W1[K-chunk y]; last block -> H ----------
// Block = 64 rows x 128 cols, K-chunk 64. LDS 51.7 KB -> 3 blocks/CU.
// Row 63 of batch tiles (pooled token) built in-staging from 24 epart chunks.
// FUSED HRED: after writing its partial slice, each block increments cnt[g]
// (device-scope); the last of the NB blocks for row-group g re-reads all NB
// slices (L2-hot), applies bias+tanh, writes the H tile. Deterministic: fixed
// p-order sum; which block executes it doesn't affect the value.
template<int CPB, int NB>
__global__ __launch_bounds__(256, 3) void k_ae1(const float* __restrict__ fm,
                                                const float* __restrict__ cls,
                                                const float* __restrict__ epart,
                                                const int* __restrict__ idxin,
                                                const float* __restrict__ W1,
                                                const float* __restrict__ b1,
                                                float* __restrict__ partial,
                                                float* __restrict__ H,
                                                int* __restrict__ cnt)
{
  __shared__ float Xs[64][68];         // 17.0 KB
  __shared__ float Ws[64][132];        // 33.8 KB
  __shared__ const float* rowptr[64];
  __shared__ int lastflag;
  int g = blockIdx.x;                  // row group: rows g*64 .. +63
  int tid = threadIdx.x;
  bool batch = (g < BB);

  if (tid < 64) {
    const float* p;
    if (batch) {
      p = (tid < KTOP) ? fm + ((size_t)g * SS + idxin[g * KEEP + tid]) * DD
                       : epart + (size_t)(g * SCH) * DD;   // placeholder (row 63 rebuilt)
    } else {
      p = cls + (size_t)tid * DD;
    }
    rowptr[tid] = p;
  }

  int ty = tid >> 5, tx = tid & 31;
  int r0 = ty * 8, c0 = tx * 4;
  float acc[8][4] = {};

  for (int cc = 0; cc < CPB; ++cc) {
    int kb = (blockIdx.y * CPB + cc) * 64;
    __syncthreads();                   // rowptr ready / previous tile consumed
#pragma unroll
    for (int i = 0; i < 4; ++i) {      // X tile: 64 rows x 16 float4
      int f4 = tid + 256 * i;
      int r = f4 >> 4, k4 = f4 & 15;
      if (!batch || r != 63)
        *(float4*)&Xs[r][k4 * 4] = *(const float4*)(rowptr[r] + kb + k4 * 4);
    }
    if (batch && tid < 16) {           // pooled-token row: sum 24 epart chunks
      float4 s = make_float4(0.f, 0.f, 0.f, 0.f);
#pragma unroll
      for (int p = 0; p < SCH; ++p) {
        float4 t = *(const float4*)(epart + (size_t)(g * SCH + p) * DD + kb + tid * 4);
        s.x += t.x; s.y += t.y; s.z += t.z; s.w += t.w;
      }
      *(float4*)&Xs[63][tid * 4] = s;
    }
#pragma unroll
    for (int i = 0; i < 8; ++i) {      // W1 chunk: 64 rows x 32 float4
      int f4 = tid + 256 * i;
      int wr = f4 >> 5, c4 = f4 & 31;
      *(float4*)&Ws[wr][c4 * 4] =
          *(const float4*)(W1 + (size_t)(kb + wr) * HH + c4 * 4);
    }
    __syncthreads();
#pragma unroll
    for (int q = 0; q < 16; ++q) {     // 64 K per chunk
      float4 xv[8], wv[4];
#pragma unroll
      for (int i = 0; i < 8; ++i) xv[i] = *(const float4*)&Xs[r0 + i][q * 4];
#pragma unroll
      for (int j = 0; j < 4; ++j) wv[j] = *(const float4*)&Ws[q * 4 + j][c0];
#pragma unroll
      for (int i = 0; i < 8; ++i) {
        float x;
        x = xv[i].x;
        acc[i][0] = fmaf(x, wv[0].x, acc[i][0]); acc[i][1] = fmaf(x, wv[0].y, acc[i][1]);
        acc[i][2] = fmaf(x, wv[0].z, acc[i][2]); acc[i][3] = fmaf(x, wv[0].w, acc[i][3]);
        x = xv[i].y;
        acc[i][0] = fmaf(x, wv[1].x, acc[i][0]); acc[i][1] = fmaf(x, wv[1].y, acc[i][1]);
        acc[i][2] = fmaf(x, wv[1].z, acc[i][2]); acc[i][3] = fmaf(x, wv[1].w, acc[i][3]);
        x = xv[i].z;
        acc[i][0] = fmaf(x, wv[2].x, acc[i][0]); acc[i][1] = fmaf(x, wv[2].y, acc[i][1]);
        acc[i][2] = fmaf(x, wv[2].z, acc[i][2]); acc[i][3] = fmaf(x, wv[2].w, acc[i][3]);
        x = xv[i].w;
        acc[i][0] = fmaf(x, wv[3].x, acc[i][0]); acc[i][1] = fmaf(x, wv[3].y, acc[i][1]);
        acc[i][2] = fmaf(x, wv[3].z, acc[i][2]); acc[i][3] = fmaf(x, wv[3].w, acc[i][3]);
      }
    }
  }
  float* P = partial + (size_t)(CPB == 1 ? blockIdx.y : 0) * ((size_t)NROW * HH);
#pragma unroll
  for (int i = 0; i < 8; ++i) {
    float4 v = make_float4(acc[i][0], acc[i][1], acc[i][2], acc[i][3]);
    *(float4*)&P[(size_t)(g * 64 + r0 + i) * HH + c0] = v;
  }

  // ---- fused hred: last-arriving block for this row-group builds H tile ----
  __threadfence();                     // release: partial writes device-visible
  if (tid == 0) {
    int prev = (NB > 1) ? atomicAdd(&cnt[g], 1) : (NB - 1);
    lastflag = (prev == NB - 1) ? 1 : 0;
  }
  __syncthreads();
  if (lastflag) {
    __threadfence();                   // acquire: no stale lines for peer slices
#pragma unroll
    for (int i = 0; i < 8; ++i) {      // 2048 float4 = 64 rows x 32 f4
      int f4 = tid + 256 * i;
      int r = f4 >> 5, c4 = f4 & 31;
      size_t off = (size_t)(g * 64 + r) * HH + c4 * 4;
      float4 s = *(const float4*)&partial[off];
#pragma unroll
      for (int p = 1; p < NB; ++p) {
        float4 t = *(const float4*)&partial[(size_t)p * ((size_t)NROW * HH) + off];
        s.x += t.x; s.y += t.y; s.z += t.z; s.w += t.w;
      }
      float4 bv = *(const float4*)&b1[c4 * 4];
      s.x = tanhf(s.x + bv.x); s.y = tanhf(s.y + bv.y);
      s.z = tanhf(s.z + bv.z); s.w = tanhf(s.w + bv.w);
      *(float4*)&H[off] = s;
    }
  }
}

// ---------------- K5: out = H @ W2 + b2 ----------------------------------------
// Block = 64 rows x 64 cols, K=128. LDS 68.6 KB -> 2 blocks/CU. grid (65, 12).
__global__ __launch_bounds__(256, 2) void k_ae2(const float* __restrict__ H,
                                                const float* __restrict__ W2,
                                                const float* __restrict__ b2,
                                                float* __restrict__ out)
{
  __shared__ float Hs[64][132];        // 33.8 KB
  __shared__ float Ws[128][68];        // 34.8 KB
  int g = blockIdx.x;
  int cb = blockIdx.y;                 // column chunk: cols cb*64 .. +63
  int tid = threadIdx.x;

#pragma unroll
  for (int i = 0; i < 8; ++i) {        // H tile: 64 rows x 32 float4
    int f4 = tid + 256 * i;
    int r = f4 >> 5, c4 = f4 & 31;
    *(float4*)&Hs[r][c4 * 4] = *(const float4*)(H + (size_t)(g * 64 + r) * HH + c4 * 4);
  }
#pragma unroll
  for (int i = 0; i < 8; ++i) {        // W2 slice: 128 rows x 16 float4
    int f4 = tid + 256 * i;
    int wr = f4 >> 4, c4 = f4 & 15;
    *(float4*)&Ws[wr][c4 * 4] =
        *(const float4*)(W2 + (size_t)wr * DD + cb * 64 + c4 * 4);
  }
  __syncthreads();

  int ty = tid >> 4, tx = tid & 15;
  int r0 = ty * 4, c0 = tx * 4;
  float acc[4][4] = {};
#pragma unroll 4
  for (int q = 0; q < 32; ++q) {       // K = 128
    float4 xv[4], wv[4];
#pragma unroll
    for (int i = 0; i < 4; ++i) xv[i] = *(const float4*)&Hs[r0 + i][q * 4];
#pragma unroll
    for (int j = 0; j < 4; ++j) wv[j] = *(const float4*)&Ws[q * 4 + j][c0];
#pragma unroll
    for (int i = 0; i < 4; ++i) {
      float x;
      x = xv[i].x;
      acc[i][0] = fmaf(x, wv[0].x, acc[i][0]); acc[i][1] = fmaf(x, wv[0].y, acc[i][1]);
      acc[i][2] = fmaf(x, wv[0].z, acc[i][2]); acc[i][3] = fmaf(x, wv[0].w, acc[i][3]);
      x = xv[i].y;
      acc[i][0] = fmaf(x, wv[1].x, acc[i][0]); acc[i][1] = fmaf(x, wv[1].y, acc[i][1]);
      acc[i][2] = fmaf(x, wv[1].z, acc[i][2]); acc[i][3] = fmaf(x, wv[1].w, acc[i][3]);
      x = xv[i].z;
      acc[i][0] = fmaf(x, wv[2].x, acc[i][0]); acc[i][1] = fmaf(x, wv[2].y, acc[i][1]);
      acc[i][2] = fmaf(x, wv[2].z, acc[i][2]); acc[i][3] = fmaf(x, wv[2].w, acc[i][3]);
      x = xv[i].w;
      acc[i][0] = fmaf(x, wv[3].x, acc[i][0]); acc[i][1] = fmaf(x, wv[3].y, acc[i][1]);
      acc[i][2] = fmaf(x, wv[3].z, acc[i][2]); acc[i][3] = fmaf(x, wv[3].w, acc[i][3]);
    }
  }
  float4 bv = *(const float4*)&b2[cb * 64 + c0];
#pragma unroll
  for (int i = 0; i < 4; ++i) {
    float4 y = make_float4(acc[i][0] + bv.x, acc[i][1] + bv.y,
                           acc[i][2] + bv.z, acc[i][3] + bv.w);
    *(float4*)&out[(size_t)(g * 64 + r0 + i) * DD + cb * 64 + c0] = y;
  }
}

extern "C" void kernel_launch(void* const* d_in, const int* in_sizes, int n_in,
                              void* d_out, int out_size, void* d_ws, size_t ws_size,
                              hipStream_t stream)
{
  const float* cls = (const float*)d_in[0];
  const float* fm  = (const float*)d_in[1];
  const float* W1  = (const float*)d_in[2];
  const float* b1  = (const float*)d_in[3];
  const float* W2  = (const float*)d_in[4];
  const float* b2  = (const float*)d_in[5];
  float* out = (float*)d_out;

  char* ws = (char*)d_ws;
  float* scores  = (float*)ws;                          //  147456 B
  int*   idx     = (int*)(ws + 147456);                 //   16384 B
  int*   cidx    = (int*)(ws + 163840);                 //  147456 B
  float* cw      = (float*)(ws + 311296);               //  147456 B
  int*   ccount  = (int*)(ws + 458752);                 //     256 B
  int*   cnt     = (int*)(ws + 459008);                 //     260 B
  float* epart   = (float*)(ws + 459776);               // 4718592 B
  float* partial = (float*)(ws + 5178368);              // NB x 2129920 B
  const size_t PSLICE = (size_t)NROW * HH * 4;          // 2129920 B

  hipLaunchKernelGGL(k_scores, dim3((BB * SS) / 4), dim3(256), 0, stream, cls, fm, scores);
  hipLaunchKernelGGL(k_rank,   dim3(BB),            dim3(576), 0, stream,
                     scores, idx, cidx, cw, ccount, cnt);
  hipLaunchKernelGGL(k_extra2, dim3(BB, SCH),       dim3(192), 0, stream,
                     cidx, cw, ccount, fm, epart);

  if (ws_size >= 5178368 + 13 * PSLICE) {               // 12 partials + H
    float* H = (float*)(ws + 5178368 + 12 * PSLICE);
    hipLaunchKernelGGL((k_ae1<1, 12>), dim3(65, 12),  dim3(256), 0, stream,
                       fm, cls, epart, idx, W1, b1, partial, H, cnt);
    hipLaunchKernelGGL(k_ae2,          dim3(65, 12),  dim3(256), 0, stream, H, W2, b2, out);
  } else {                                              // small-ws fallback
    float* H = (float*)(ws + 5178368 + PSLICE);
    hipLaunchKernelGGL((k_ae1<12, 1>), dim3(65, 1),   dim3(256), 0, stream,
                       fm, cls, epart, idx, W1, b1, partial, H, cnt);
    hipLaunchKernelGGL(k_ae2,          dim3(65, 12),  dim3(256), 0, stream, H, W2, b2, out);
  }
}

// Round 14
// 90.032 us; speedup vs baseline: 2.0579x; 2.0579x over previous
//
#include <hip/hip_runtime.h>
#include <math.h>

#define BB   64
#define SS   576
#define DD   768
#define KTOP 63
#define KEEP 64
#define HH   128
#define NROW (BB*KEEP + BB)   // 4160 = 65*64
#define SCH  24               // pooled-sum chunk count (grid.y)

typedef unsigned long long ull;

// ---------------- K1: cls attention scores (f64 accumulate for exact ranking) ---
__global__ __launch_bounds__(256) void k_scores(const float* __restrict__ cls,
                                                const float* __restrict__ fm,
                                                float* __restrict__ scores)
{
  int gw = (blockIdx.x * blockDim.x + threadIdx.x) >> 6;   // one wave per (b,s)
  int lane = threadIdx.x & 63;
  if (gw >= BB * SS) return;
  int b = gw / SS, s = gw - b * SS;
  const float4* frow = (const float4*)(fm + ((size_t)b * SS + s) * DD);
  const float4* crow = (const float4*)(cls + (size_t)b * DD);
  double acc = 0.0;
#pragma unroll
  for (int j = 0; j < 3; ++j) {
    float4 f = frow[lane + 64 * j];
    float4 c = crow[lane + 64 * j];
    acc += (double)f.x * c.x + (double)f.y * c.y + (double)f.z * c.z + (double)f.w * c.w;
  }
#pragma unroll
  for (int off = 32; off > 0; off >>= 1) acc += __shfl_down(acc, off, 64);
  if (lane == 0) scores[(size_t)b * SS + s] = (float)acc;
}

// ---------------- K2: rank top-63 + softmax weights + survivor compaction ------
// One 576-thread block per batch. rank = #{keys > key_s} (unique keys -> exact
// jax.lax.top_k order). w' = e/Z (0 for selected, matching f32 exp(-1e4)
// underflow). Rows with w' > 1e-10 are compacted (stable, ascending s) into
// (cidx, cw); skipped mass <= ~5e-9 (measured: absmax identical to dense).
__global__ __launch_bounds__(576) void k_rank(const float* __restrict__ scores,
                                              int* __restrict__ idxout,
                                              int* __restrict__ cidx,
                                              float* __restrict__ cw,
                                              int* __restrict__ ccount)
{
  __shared__ ull keys[SS];
  __shared__ float redm[9], redz[9];
  __shared__ unsigned wcnt[9];
  int b = blockIdx.x, tid = threadIdx.x;          // tid == s (0..575)
  int lane = tid & 63, wid = tid >> 6;            // 9 waves
  float sc = scores[(size_t)b * SS + tid];
  unsigned int u = __float_as_uint(sc);
  u = (u & 0x80000000u) ? ~u : (u | 0x80000000u); // order-preserving map
  ull key = ((ull)u << 32) | (ull)(0xFFFFFFFFu - (unsigned)tid);
  keys[tid] = key;
  __syncthreads();
  int rank = 0;
#pragma unroll 8
  for (int s = 0; s < SS; ++s) rank += (keys[s] > key) ? 1 : 0;   // LDS broadcast
  bool sel = rank < KTOP;
  if (sel) idxout[b * KEEP + rank] = tid;
  // max over unselected (selected logits are sc-10000 -> never the max)
  float m = sel ? -1e30f : sc;
#pragma unroll
  for (int off = 32; off; off >>= 1) m = fmaxf(m, __shfl_xor(m, off, 64));
  if (lane == 0) redm[wid] = m;
  __syncthreads();
  float M = redm[0];
#pragma unroll
  for (int i = 1; i < 9; ++i) M = fmaxf(M, redm[i]);
  float e = sel ? 0.f : expf(sc - M);
  float z = e;
#pragma unroll
  for (int off = 32; off; off >>= 1) z += __shfl_xor(z, off, 64);
  if (lane == 0) redz[wid] = z;
  __syncthreads();
  float Z = redz[0];
#pragma unroll
  for (int i = 1; i < 9; ++i) Z += redz[i];
  float w = e / Z;
  // ---- compaction of survivors ----
  bool keep = w > 1e-10f;
  ull ball = __ballot(keep);
  int wpre = __popcll(ball & ((1ull << lane) - 1ull));
  if (lane == 0) wcnt[wid] = (unsigned)__popcll(ball);
  __syncthreads();
  int base = 0;
#pragma unroll
  for (int i = 0; i < 9; ++i) base += (i < wid) ? (int)wcnt[i] : 0;
  if (keep) {
    int pos = base + wpre;
    cidx[(size_t)b * SS + pos] = tid;
    cw[(size_t)b * SS + pos] = w;
  }
  if (tid == 0) {
    int tot = 0;
#pragma unroll
    for (int i = 0; i < 9; ++i) tot += (int)wcnt[i];
    ccount[b] = tot;
  }
}

// ---------------- K3: sparse pooled-token partial sums -------------------------
// grid (64, 24) x 192 thr. Chunk p sums survivor rows r = p, p+24, ... Each row
// read is a coalesced 3 KB segment (192 x float4).
__global__ __launch_bounds__(192) void k_extra2(const int* __restrict__ cidx,
                                                const float* __restrict__ cw,
                                                const int* __restrict__ ccount,
                                                const float* __restrict__ fm,
                                                float* __restrict__ epart)
{
  int b = blockIdx.x, p = blockIdx.y, tid = threadIdx.x;   // tid = float4 col
  int n = ccount[b];
  const float* fb = fm + (size_t)b * SS * DD + tid * 4;
  float4 acc = make_float4(0.f, 0.f, 0.f, 0.f);
  for (int r = p; r < n; r += SCH) {
    float w = cw[(size_t)b * SS + r];                      // uniform broadcast
    int s = cidx[(size_t)b * SS + r];
    float4 v = *(const float4*)(fb + (size_t)s * DD);
    acc.x = fmaf(w, v.x, acc.x); acc.y = fmaf(w, v.y, acc.y);
    acc.z = fmaf(w, v.z, acc.z); acc.w = fmaf(w, v.w, acc.w);
  }
  *(float4*)(epart + (size_t)(b * SCH + p) * DD + tid * 4) = acc;
}

// ---------------- K4: partial[y] = X(rows) @ W1[K-chunk y] ---------------------
// Block = 64 rows x 128 cols, K-chunk 64. LDS 51.7 KB -> 3 blocks/CU.
// Row 63 of batch tiles (pooled token) is built in-staging as the sum of the 24
// epart chunk rows (16 threads, off the critical staging path).
template<int CPB>
__global__ __launch_bounds__(256, 3) void k_ae1(const float* __restrict__ fm,
                                                const float* __restrict__ cls,
                                                const float* __restrict__ epart,
                                                const int* __restrict__ idxin,
                                                const float* __restrict__ W1,
                                                float* __restrict__ partial)
{
  __shared__ float Xs[64][68];         // 17.0 KB
  __shared__ float Ws[64][132];        // 33.8 KB
  __shared__ const float* rowptr[64];
  int g = blockIdx.x;                  // row group: rows g*64 .. +63
  int tid = threadIdx.x;
  bool batch = (g < BB);

  if (tid < 64) {
    const float* p;
    if (batch) {
      p = (tid < KTOP) ? fm + ((size_t)g * SS + idxin[g * KEEP + tid]) * DD
                       : epart + (size_t)(g * SCH) * DD;   // placeholder (row 63 rebuilt)
    } else {
      p = cls + (size_t)tid * DD;
    }
    rowptr[tid] = p;
  }

  int ty = tid >> 5, tx = tid & 31;
  int r0 = ty * 8, c0 = tx * 4;
  float acc[8][4] = {};

  for (int cc = 0; cc < CPB; ++cc) {
    int kb = (blockIdx.y * CPB + cc) * 64;
    __syncthreads();                   // rowptr ready / previous tile consumed
#pragma unroll
    for (int i = 0; i < 4; ++i) {      // X tile: 64 rows x 16 float4
      int f4 = tid + 256 * i;
      int r = f4 >> 4, k4 = f4 & 15;
      if (!batch || r != 63)
        *(float4*)&Xs[r][k4 * 4] = *(const float4*)(rowptr[r] + kb + k4 * 4);
    }
    if (batch && tid < 16) {           // pooled-token row: sum 24 epart chunks
      float4 s = make_float4(0.f, 0.f, 0.f, 0.f);
#pragma unroll
      for (int p = 0; p < SCH; ++p) {
        float4 t = *(const float4*)(epart + (size_t)(g * SCH + p) * DD + kb + tid * 4);
        s.x += t.x; s.y += t.y; s.z += t.z; s.w += t.w;
      }
      *(float4*)&Xs[63][tid * 4] = s;
    }
#pragma unroll
    for (int i = 0; i < 8; ++i) {      // W1 chunk: 64 rows x 32 float4
      int f4 = tid + 256 * i;
      int wr = f4 >> 5, c4 = f4 & 31;
      *(float4*)&Ws[wr][c4 * 4] =
          *(const float4*)(W1 + (size_t)(kb + wr) * HH + c4 * 4);
    }
    __syncthreads();
#pragma unroll
    for (int q = 0; q < 16; ++q) {     // 64 K per chunk
      float4 xv[8], wv[4];
#pragma unroll
      for (int i = 0; i < 8; ++i) xv[i] = *(const float4*)&Xs[r0 + i][q * 4];
#pragma unroll
      for (int j = 0; j < 4; ++j) wv[j] = *(const float4*)&Ws[q * 4 + j][c0];
#pragma unroll
      for (int i = 0; i < 8; ++i) {
        float x;
        x = xv[i].x;
        acc[i][0] = fmaf(x, wv[0].x, acc[i][0]); acc[i][1] = fmaf(x, wv[0].y, acc[i][1]);
        acc[i][2] = fmaf(x, wv[0].z, acc[i][2]); acc[i][3] = fmaf(x, wv[0].w, acc[i][3]);
        x = xv[i].y;
        acc[i][0] = fmaf(x, wv[1].x, acc[i][0]); acc[i][1] = fmaf(x, wv[1].y, acc[i][1]);
        acc[i][2] = fmaf(x, wv[1].z, acc[i][2]); acc[i][3] = fmaf(x, wv[1].w, acc[i][3]);
        x = xv[i].z;
        acc[i][0] = fmaf(x, wv[2].x, acc[i][0]); acc[i][1] = fmaf(x, wv[2].y, acc[i][1]);
        acc[i][2] = fmaf(x, wv[2].z, acc[i][2]); acc[i][3] = fmaf(x, wv[2].w, acc[i][3]);
        x = xv[i].w;
        acc[i][0] = fmaf(x, wv[3].x, acc[i][0]); acc[i][1] = fmaf(x, wv[3].y, acc[i][1]);
        acc[i][2] = fmaf(x, wv[3].z, acc[i][2]); acc[i][3] = fmaf(x, wv[3].w, acc[i][3]);
      }
    }
  }
  float* P = partial + (size_t)blockIdx.y * ((size_t)NROW * HH);
#pragma unroll
  for (int i = 0; i < 8; ++i) {
    float4 v = make_float4(acc[i][0], acc[i][1], acc[i][2], acc[i][3]);
    *(float4*)&P[(size_t)(g * 64 + r0 + i) * HH + c0] = v;
  }
}

// ---------------- K5: H = tanh(sum(partials) + b1) -----------------------------
template<int NP>
__global__ __launch_bounds__(256) void k_hred(const float* __restrict__ partial,
                                              const float* __restrict__ b1,
                                              float* __restrict__ H)
{
  int i4 = blockIdx.x * 256 + threadIdx.x;          // float4 index, 133120 total
  const float4* P = (const float4*)partial;
  float4 s = P[i4];
#pragma unroll
  for (int p = 1; p < NP; ++p) {
    float4 t = P[(size_t)p * (NROW * HH / 4) + i4];
    s.x += t.x; s.y += t.y; s.z += t.z; s.w += t.w;
  }
  float4 bv = ((const float4*)b1)[i4 & 31];         // HH/4 = 32 float4 per row
  s.x = tanhf(s.x + bv.x); s.y = tanhf(s.y + bv.y);
  s.z = tanhf(s.z + bv.z); s.w = tanhf(s.w + bv.w);
  ((float4*)H)[i4] = s;
}

// ---------------- K6: out = H @ W2 + b2 ----------------------------------------
// Block = 64 rows x 64 cols, K=128. LDS 68.6 KB -> 2 blocks/CU. grid (65, 12).
__global__ __launch_bounds__(256, 2) void k_ae2(const float* __restrict__ H,
                                                const float* __restrict__ W2,
                                                const float* __restrict__ b2,
                                                float* __restrict__ out)
{
  __shared__ float Hs[64][132];        // 33.8 KB
  __shared__ float Ws[128][68];        // 34.8 KB
  int g = blockIdx.x;
  int cb = blockIdx.y;                 // column chunk: cols cb*64 .. +63
  int tid = threadIdx.x;

#pragma unroll
  for (int i = 0; i < 8; ++i) {        // H tile: 64 rows x 32 float4
    int f4 = tid + 256 * i;
    int r = f4 >> 5, c4 = f4 & 31;
    *(float4*)&Hs[r][c4 * 4] = *(const float4*)(H + (size_t)(g * 64 + r) * HH + c4 * 4);
  }
#pragma unroll
  for (int i = 0; i < 8; ++i) {        // W2 slice: 128 rows x 16 float4
    int f4 = tid + 256 * i;
    int wr = f4 >> 4, c4 = f4 & 15;
    *(float4*)&Ws[wr][c4 * 4] =
        *(const float4*)(W2 + (size_t)wr * DD + cb * 64 + c4 * 4);
  }
  __syncthreads();

  int ty = tid >> 4, tx = tid & 15;
  int r0 = ty * 4, c0 = tx * 4;
  float acc[4][4] = {};
#pragma unroll 4
  for (int q = 0; q < 32; ++q) {       // K = 128
    float4 xv[4], wv[4];
#pragma unroll
    for (int i = 0; i < 4; ++i) xv[i] = *(const float4*)&Hs[r0 + i][q * 4];
#pragma unroll
    for (int j = 0; j < 4; ++j) wv[j] = *(const float4*)&Ws[q * 4 + j][c0];
#pragma unroll
    for (int i = 0; i < 4; ++i) {
      float x;
      x = xv[i].x;
      acc[i][0] = fmaf(x, wv[0].x, acc[i][0]); acc[i][1] = fmaf(x, wv[0].y, acc[i][1]);
      acc[i][2] = fmaf(x, wv[0].z, acc[i][2]); acc[i][3] = fmaf(x, wv[0].w, acc[i][3]);
      x = xv[i].y;
      acc[i][0] = fmaf(x, wv[1].x, acc[i][0]); acc[i][1] = fmaf(x, wv[1].y, acc[i][1]);
      acc[i][2] = fmaf(x, wv[1].z, acc[i][2]); acc[i][3] = fmaf(x, wv[1].w, acc[i][3]);
      x = xv[i].z;
      acc[i][0] = fmaf(x, wv[2].x, acc[i][0]); acc[i][1] = fmaf(x, wv[2].y, acc[i][1]);
      acc[i][2] = fmaf(x, wv[2].z, acc[i][2]); acc[i][3] = fmaf(x, wv[2].w, acc[i][3]);
      x = xv[i].w;
      acc[i][0] = fmaf(x, wv[3].x, acc[i][0]); acc[i][1] = fmaf(x, wv[3].y, acc[i][1]);
      acc[i][2] = fmaf(x, wv[3].z, acc[i][2]); acc[i][3] = fmaf(x, wv[3].w, acc[i][3]);
    }
  }
  float4 bv = *(const float4*)&b2[cb * 64 + c0];
#pragma unroll
  for (int i = 0; i < 4; ++i) {
    float4 y = make_float4(acc[i][0] + bv.x, acc[i][1] + bv.y,
                           acc[i][2] + bv.z, acc[i][3] + bv.w);
    *(float4*)&out[(size_t)(g * 64 + r0 + i) * DD + cb * 64 + c0] = y;
  }
}

extern "C" void kernel_launch(void* const* d_in, const int* in_sizes, int n_in,
                              void* d_out, int out_size, void* d_ws, size_t ws_size,
                              hipStream_t stream)
{
  const float* cls = (const float*)d_in[0];
  const float* fm  = (const float*)d_in[1];
  const float* W1  = (const float*)d_in[2];
  const float* b1  = (const float*)d_in[3];
  const float* W2  = (const float*)d_in[4];
  const float* b2  = (const float*)d_in[5];
  float* out = (float*)d_out;

  char* ws = (char*)d_ws;
  float* scores  = (float*)ws;                          //  147456 B
  int*   idx     = (int*)(ws + 147456);                 //   16384 B
  int*   cidx    = (int*)(ws + 163840);                 //  147456 B
  float* cw      = (float*)(ws + 311296);               //  147456 B
  int*   ccount  = (int*)(ws + 458752);                 //    1024 B
  float* epart   = (float*)(ws + 459776);               // 4718592 B
  float* partial = (float*)(ws + 5178368);              // NP x 2129920 B
  const size_t PSLICE = (size_t)NROW * HH * 4;          // 2129920 B

  hipLaunchKernelGGL(k_scores, dim3((BB * SS) / 4), dim3(256), 0, stream, cls, fm, scores);
  hipLaunchKernelGGL(k_rank,   dim3(BB),            dim3(576), 0, stream,
                     scores, idx, cidx, cw, ccount);
  hipLaunchKernelGGL(k_extra2, dim3(BB, SCH),       dim3(192), 0, stream,
                     cidx, cw, ccount, fm, epart);

  if (ws_size >= 5178368 + 13 * PSLICE) {               // 12 partials + H
    float* H = (float*)(ws + 5178368 + 12 * PSLICE);
    hipLaunchKernelGGL(k_ae1<1>,  dim3(65, 12),      dim3(256), 0, stream,
                       fm, cls, epart, idx, W1, partial);
    hipLaunchKernelGGL(k_hred<12>, dim3(NROW * HH / 1024), dim3(256), 0, stream,
                       partial, b1, H);
    hipLaunchKernelGGL(k_ae2,     dim3(65, 12),      dim3(256), 0, stream, H, W2, b2, out);
  } else {                                              // small-ws fallback
    float* H = (float*)(ws + 5178368 + PSLICE);
    hipLaunchKernelGGL(k_ae1<12>, dim3(65, 1),       dim3(256), 0, stream,
                       fm, cls, epart, idx, W1, partial);
    hipLaunchKernelGGL(k_hred<1>, dim3(NROW * HH / 1024), dim3(256), 0, stream,
                       partial, b1, H);
    hipLaunchKernelGGL(k_ae2,     dim3(65, 12),      dim3(256), 0, stream, H, W2, b2, out);
  }
}

// Round 15
// 87.746 us; speedup vs baseline: 2.1116x; 1.0260x over previous
//
#include <hip/hip_runtime.h>
#include <math.h>

#define BB   64
#define SS   576
#define DD   768
#define KTOP 63
#define KEEP 64
#define HH   128
#define NROW (BB*KEEP + BB)   // 4160 = 65*64
#define SCH  24               // pooled-sum chunk count (grid.y)

typedef unsigned long long ull;

// ---------------- K1: cls attention scores (f64 accumulate for exact ranking) ---
__global__ __launch_bounds__(256) void k_scores(const float* __restrict__ cls,
                                                const float* __restrict__ fm,
                                                float* __restrict__ scores)
{
  int gw = (blockIdx.x * blockDim.x + threadIdx.x) >> 6;   // one wave per (b,s)
  int lane = threadIdx.x & 63;
  if (gw >= BB * SS) return;
  int b = gw / SS, s = gw - b * SS;
  const float4* frow = (const float4*)(fm + ((size_t)b * SS + s) * DD);
  const float4* crow = (const float4*)(cls + (size_t)b * DD);
  double acc = 0.0;
#pragma unroll
  for (int j = 0; j < 3; ++j) {
    float4 f = frow[lane + 64 * j];
    float4 c = crow[lane + 64 * j];
    acc += (double)f.x * c.x + (double)f.y * c.y + (double)f.z * c.z + (double)f.w * c.w;
  }
#pragma unroll
  for (int off = 32; off > 0; off >>= 1) acc += __shfl_down(acc, off, 64);
  if (lane == 0) scores[(size_t)b * SS + s] = (float)acc;
}

// ---------------- K2: rank top-63 + softmax weights + survivor compaction ------
// One 576-thread block per batch. rank = #{keys > key_s} (unique keys -> exact
// jax.lax.top_k order). w' = e/Z (0 for selected, matching f32 exp(-1e4)
// underflow). Rows with w' > 1e-10 are compacted (stable, ascending s) into
// (cidx, cw); skipped mass <= ~5e-9 (measured: absmax identical to dense).
__global__ __launch_bounds__(576) void k_rank(const float* __restrict__ scores,
                                              int* __restrict__ idxout,
                                              int* __restrict__ cidx,
                                              float* __restrict__ cw,
                                              int* __restrict__ ccount)
{
  __shared__ ull keys[SS];
  __shared__ float redm[9], redz[9];
  __shared__ unsigned wcnt[9];
  int b = blockIdx.x, tid = threadIdx.x;          // tid == s (0..575)
  int lane = tid & 63, wid = tid >> 6;            // 9 waves
  float sc = scores[(size_t)b * SS + tid];
  unsigned int u = __float_as_uint(sc);
  u = (u & 0x80000000u) ? ~u : (u | 0x80000000u); // order-preserving map
  ull key = ((ull)u << 32) | (ull)(0xFFFFFFFFu - (unsigned)tid);
  keys[tid] = key;
  __syncthreads();
  int rank = 0;
#pragma unroll 8
  for (int s = 0; s < SS; ++s) rank += (keys[s] > key) ? 1 : 0;   // LDS broadcast
  bool sel = rank < KTOP;
  if (sel) idxout[b * KEEP + rank] = tid;
  // max over unselected (selected logits are sc-10000 -> never the max)
  float m = sel ? -1e30f : sc;
#pragma unroll
  for (int off = 32; off; off >>= 1) m = fmaxf(m, __shfl_xor(m, off, 64));
  if (lane == 0) redm[wid] = m;
  __syncthreads();
  float M = redm[0];
#pragma unroll
  for (int i = 1; i < 9; ++i) M = fmaxf(M, redm[i]);
  float e = sel ? 0.f : expf(sc - M);
  float z = e;
#pragma unroll
  for (int off = 32; off; off >>= 1) z += __shfl_xor(z, off, 64);
  if (lane == 0) redz[wid] = z;
  __syncthreads();
  float Z = redz[0];
#pragma unroll
  for (int i = 1; i < 9; ++i) Z += redz[i];
  float w = e / Z;
  // ---- compaction of survivors ----
  bool keep = w > 1e-10f;
  ull ball = __ballot(keep);
  int wpre = __popcll(ball & ((1ull << lane) - 1ull));
  if (lane == 0) wcnt[wid] = (unsigned)__popcll(ball);
  __syncthreads();
  int base = 0;
#pragma unroll
  for (int i = 0; i < 9; ++i) base += (i < wid) ? (int)wcnt[i] : 0;
  if (keep) {
    int pos = base + wpre;
    cidx[(size_t)b * SS + pos] = tid;
    cw[(size_t)b * SS + pos] = w;
  }
  if (tid == 0) {
    int tot = 0;
#pragma unroll
    for (int i = 0; i < 9; ++i) tot += (int)wcnt[i];
    ccount[b] = tot;
  }
}

// ---------------- K3: sparse pooled-token partial sums -------------------------
// grid (64, 24) x 192 thr. Chunk p sums survivor rows r = p, p+24, ... Each row
// read is a coalesced 3 KB segment (192 x float4).
__global__ __launch_bounds__(192) void k_extra2(const int* __restrict__ cidx,
                                                const float* __restrict__ cw,
                                                const int* __restrict__ ccount,
                                                const float* __restrict__ fm,
                                                float* __restrict__ epart)
{
  int b = blockIdx.x, p = blockIdx.y, tid = threadIdx.x;   // tid = float4 col
  int n = ccount[b];
  const float* fb = fm + (size_t)b * SS * DD + tid * 4;
  float4 acc = make_float4(0.f, 0.f, 0.f, 0.f);
  for (int r = p; r < n; r += SCH) {
    float w = cw[(size_t)b * SS + r];                      // uniform broadcast
    int s = cidx[(size_t)b * SS + r];
    float4 v = *(const float4*)(fb + (size_t)s * DD);
    acc.x = fmaf(w, v.x, acc.x); acc.y = fmaf(w, v.y, acc.y);
    acc.z = fmaf(w, v.z, acc.z); acc.w = fmaf(w, v.w, acc.w);
  }
  *(float4*)(epart + (size_t)(b * SCH + p) * DD + tid * 4) = acc;
}

// ---------------- K4: partial[y] = X(rows) @ W1[2 K-chunks y] ------------------
// Block = 64 rows x 128 cols, CPB K-chunks of 64 (CPB=2 -> grid (65,6), 390
// blocks all resident at 3 blocks/CU; halves partial-store traffic vs CPB=1).
// LDS 51.7 KB. Row 63 of batch tiles (pooled token) built in-staging from the
// 24 epart chunks (16 threads, off the critical staging path).
template<int CPB>
__global__ __launch_bounds__(256, 3) void k_ae1(const float* __restrict__ fm,
                                                const float* __restrict__ cls,
                                                const float* __restrict__ epart,
                                                const int* __restrict__ idxin,
                                                const float* __restrict__ W1,
                                                float* __restrict__ partial)
{
  __shared__ float Xs[64][68];         // 17.0 KB
  __shared__ float Ws[64][132];        // 33.8 KB
  __shared__ const float* rowptr[64];
  int g = blockIdx.x;                  // row group: rows g*64 .. +63
  int tid = threadIdx.x;
  bool batch = (g < BB);

  if (tid < 64) {
    const float* p;
    if (batch) {
      p = (tid < KTOP) ? fm + ((size_t)g * SS + idxin[g * KEEP + tid]) * DD
                       : epart + (size_t)(g * SCH) * DD;   // placeholder (row 63 rebuilt)
    } else {
      p = cls + (size_t)tid * DD;
    }
    rowptr[tid] = p;
  }

  int ty = tid >> 5, tx = tid & 31;
  int r0 = ty * 8, c0 = tx * 4;
  float acc[8][4] = {};

  for (int cc = 0; cc < CPB; ++cc) {
    int kb = (blockIdx.y * CPB + cc) * 64;
    __syncthreads();                   // rowptr ready / previous tile consumed
#pragma unroll
    for (int i = 0; i < 4; ++i) {      // X tile: 64 rows x 16 float4
      int f4 = tid + 256 * i;
      int r = f4 >> 4, k4 = f4 & 15;
      if (!batch || r != 63)
        *(float4*)&Xs[r][k4 * 4] = *(const float4*)(rowptr[r] + kb + k4 * 4);
    }
    if (batch && tid < 16) {           // pooled-token row: sum 24 epart chunks
      float4 s = make_float4(0.f, 0.f, 0.f, 0.f);
#pragma unroll
      for (int p = 0; p < SCH; ++p) {
        float4 t = *(const float4*)(epart + (size_t)(g * SCH + p) * DD + kb + tid * 4);
        s.x += t.x; s.y += t.y; s.z += t.z; s.w += t.w;
      }
      *(float4*)&Xs[63][tid * 4] = s;
    }
#pragma unroll
    for (int i = 0; i < 8; ++i) {      // W1 chunk: 64 rows x 32 float4
      int f4 = tid + 256 * i;
      int wr = f4 >> 5, c4 = f4 & 31;
      *(float4*)&Ws[wr][c4 * 4] =
          *(const float4*)(W1 + (size_t)(kb + wr) * HH + c4 * 4);
    }
    __syncthreads();
#pragma unroll
    for (int q = 0; q < 16; ++q) {     // 64 K per chunk
      float4 xv[8], wv[4];
#pragma unroll
      for (int i = 0; i < 8; ++i) xv[i] = *(const float4*)&Xs[r0 + i][q * 4];
#pragma unroll
      for (int j = 0; j < 4; ++j) wv[j] = *(const float4*)&Ws[q * 4 + j][c0];
#pragma unroll
      for (int i = 0; i < 8; ++i) {
        float x;
        x = xv[i].x;
        acc[i][0] = fmaf(x, wv[0].x, acc[i][0]); acc[i][1] = fmaf(x, wv[0].y, acc[i][1]);
        acc[i][2] = fmaf(x, wv[0].z, acc[i][2]); acc[i][3] = fmaf(x, wv[0].w, acc[i][3]);
        x = xv[i].y;
        acc[i][0] = fmaf(x, wv[1].x, acc[i][0]); acc[i][1] = fmaf(x, wv[1].y, acc[i][1]);
        acc[i][2] = fmaf(x, wv[1].z, acc[i][2]); acc[i][3] = fmaf(x, wv[1].w, acc[i][3]);
        x = xv[i].z;
        acc[i][0] = fmaf(x, wv[2].x, acc[i][0]); acc[i][1] = fmaf(x, wv[2].y, acc[i][1]);
        acc[i][2] = fmaf(x, wv[2].z, acc[i][2]); acc[i][3] = fmaf(x, wv[2].w, acc[i][3]);
        x = xv[i].w;
        acc[i][0] = fmaf(x, wv[3].x, acc[i][0]); acc[i][1] = fmaf(x, wv[3].y, acc[i][1]);
        acc[i][2] = fmaf(x, wv[3].z, acc[i][2]); acc[i][3] = fmaf(x, wv[3].w, acc[i][3]);
      }
    }
  }
  float* P = partial + (size_t)blockIdx.y * ((size_t)NROW * HH);
#pragma unroll
  for (int i = 0; i < 8; ++i) {
    float4 v = make_float4(acc[i][0], acc[i][1], acc[i][2], acc[i][3]);
    *(float4*)&P[(size_t)(g * 64 + r0 + i) * HH + c0] = v;
  }
}

// ---------------- K5: H = tanh(sum(partials) + b1) -----------------------------
template<int NP>
__global__ __launch_bounds__(256) void k_hred(const float* __restrict__ partial,
                                              const float* __restrict__ b1,
                                              float* __restrict__ H)
{
  int i4 = blockIdx.x * 256 + threadIdx.x;          // float4 index, 133120 total
  const float4* P = (const float4*)partial;
  float4 s = P[i4];
#pragma unroll
  for (int p = 1; p < NP; ++p) {
    float4 t = P[(size_t)p * (NROW * HH / 4) + i4];
    s.x += t.x; s.y += t.y; s.z += t.z; s.w += t.w;
  }
  float4 bv = ((const float4*)b1)[i4 & 31];         // HH/4 = 32 float4 per row
  s.x = tanhf(s.x + bv.x); s.y = tanhf(s.y + bv.y);
  s.z = tanhf(s.z + bv.z); s.w = tanhf(s.w + bv.w);
  ((float4*)H)[i4] = s;
}

// ---------------- K6: out = H @ W2 + b2 ----------------------------------------
// Block = 64 rows x 64 cols, K=128. LDS 68.6 KB -> 2 blocks/CU. grid (65, 12).
__global__ __launch_bounds__(256, 2) void k_ae2(const float* __restrict__ H,
                                                const float* __restrict__ W2,
                                                const float* __restrict__ b2,
                                                float* __restrict__ out)
{
  __shared__ float Hs[64][132];        // 33.8 KB
  __shared__ float Ws[128][68];        // 34.8 KB
  int g = blockIdx.x;
  int cb = blockIdx.y;                 // column chunk: cols cb*64 .. +63
  int tid = threadIdx.x;

#pragma unroll
  for (int i = 0; i < 8; ++i) {        // H tile: 64 rows x 32 float4
    int f4 = tid + 256 * i;
    int r = f4 >> 5, c4 = f4 & 31;
    *(float4*)&Hs[r][c4 * 4] = *(const float4*)(H + (size_t)(g * 64 + r) * HH + c4 * 4);
  }
#pragma unroll
  for (int i = 0; i < 8; ++i) {        // W2 slice: 128 rows x 16 float4
    int f4 = tid + 256 * i;
    int wr = f4 >> 4, c4 = f4 & 15;
    *(float4*)&Ws[wr][c4 * 4] =
        *(const float4*)(W2 + (size_t)wr * DD + cb * 64 + c4 * 4);
  }
  __syncthreads();

  int ty = tid >> 4, tx = tid & 15;
  int r0 = ty * 4, c0 = tx * 4;
  float acc[4][4] = {};
#pragma unroll 4
  for (int q = 0; q < 32; ++q) {       // K = 128
    float4 xv[4], wv[4];
#pragma unroll
    for (int i = 0; i < 4; ++i) xv[i] = *(const float4*)&Hs[r0 + i][q * 4];
#pragma unroll
    for (int j = 0; j < 4; ++j) wv[j] = *(const float4*)&Ws[q * 4 + j][c0];
#pragma unroll
    for (int i = 0; i < 4; ++i) {
      float x;
      x = xv[i].x;
      acc[i][0] = fmaf(x, wv[0].x, acc[i][0]); acc[i][1] = fmaf(x, wv[0].y, acc[i][1]);
      acc[i][2] = fmaf(x, wv[0].z, acc[i][2]); acc[i][3] = fmaf(x, wv[0].w, acc[i][3]);
      x = xv[i].y;
      acc[i][0] = fmaf(x, wv[1].x, acc[i][0]); acc[i][1] = fmaf(x, wv[1].y, acc[i][1]);
      acc[i][2] = fmaf(x, wv[1].z, acc[i][2]); acc[i][3] = fmaf(x, wv[1].w, acc[i][3]);
      x = xv[i].z;
      acc[i][0] = fmaf(x, wv[2].x, acc[i][0]); acc[i][1] = fmaf(x, wv[2].y, acc[i][1]);
      acc[i][2] = fmaf(x, wv[2].z, acc[i][2]); acc[i][3] = fmaf(x, wv[2].w, acc[i][3]);
      x = xv[i].w;
      acc[i][0] = fmaf(x, wv[3].x, acc[i][0]); acc[i][1] = fmaf(x, wv[3].y, acc[i][1]);
      acc[i][2] = fmaf(x, wv[3].z, acc[i][2]); acc[i][3] = fmaf(x, wv[3].w, acc[i][3]);
    }
  }
  float4 bv = *(const float4*)&b2[cb * 64 + c0];
#pragma unroll
  for (int i = 0; i < 4; ++i) {
    float4 y = make_float4(acc[i][0] + bv.x, acc[i][1] + bv.y,
                           acc[i][2] + bv.z, acc[i][3] + bv.w);
    *(float4*)&out[(size_t)(g * 64 + r0 + i) * DD + cb * 64 + c0] = y;
  }
}

extern "C" void kernel_launch(void* const* d_in, const int* in_sizes, int n_in,
                              void* d_out, int out_size, void* d_ws, size_t ws_size,
                              hipStream_t stream)
{
  const float* cls = (const float*)d_in[0];
  const float* fm  = (const float*)d_in[1];
  const float* W1  = (const float*)d_in[2];
  const float* b1  = (const float*)d_in[3];
  const float* W2  = (const float*)d_in[4];
  const float* b2  = (const float*)d_in[5];
  float* out = (float*)d_out;

  char* ws = (char*)d_ws;
  float* scores  = (float*)ws;                          //  147456 B
  int*   idx     = (int*)(ws + 147456);                 //   16384 B
  int*   cidx    = (int*)(ws + 163840);                 //  147456 B
  float* cw      = (float*)(ws + 311296);               //  147456 B
  int*   ccount  = (int*)(ws + 458752);                 //    1024 B
  float* epart   = (float*)(ws + 459776);               // 4718592 B
  float* partial = (float*)(ws + 5178368);              // NP x 2129920 B
  const size_t PSLICE = (size_t)NROW * HH * 4;          // 2129920 B

  hipLaunchKernelGGL(k_scores, dim3((BB * SS) / 4), dim3(256), 0, stream, cls, fm, scores);
  hipLaunchKernelGGL(k_rank,   dim3(BB),            dim3(576), 0, stream,
                     scores, idx, cidx, cw, ccount);
  hipLaunchKernelGGL(k_extra2, dim3(BB, SCH),       dim3(192), 0, stream,
                     cidx, cw, ccount, fm, epart);

  if (ws_size >= 5178368 + 7 * PSLICE) {                // 6 partials + H
    float* H = (float*)(ws + 5178368 + 6 * PSLICE);
    hipLaunchKernelGGL(k_ae1<2>,  dim3(65, 6),       dim3(256), 0, stream,
                       fm, cls, epart, idx, W1, partial);
    hipLaunchKernelGGL(k_hred<6>, dim3(NROW * HH / 1024), dim3(256), 0, stream,
                       partial, b1, H);
    hipLaunchKernelGGL(k_ae2,     dim3(65, 12),      dim3(256), 0, stream, H, W2, b2, out);
  } else {                                              // small-ws fallback
    float* H = (float*)(ws + 5178368 + PSLICE);
    hipLaunchKernelGGL(k_ae1<12>, dim3(65, 1),       dim3(256), 0, stream,
                       fm, cls, epart, idx, W1, partial);
    hipLaunchKernelGGL(k_hred<1>, dim3(NROW * HH / 1024), dim3(256), 0, stream,
                       partial, b1, H);
    hipLaunchKernelGGL(k_ae2,     dim3(65, 12),      dim3(256), 0, stream, H, W2, b2, out);
  }
}